// Round 1
// baseline (110.977 us; speedup 1.0000x reference)
//
#include <hip/hip_runtime.h>

// Path signature depth-3 for path (N=32, L=128, C=48) fp32.
//
// Math: with increments v_t = p[t+1]-p[t], prefix P_t = p[t]-p[0] (telescoped),
//   G_t[i] = P_t[i] + v_t[i]/2
//   R_t[i] = P_t[i]/2 + v_t[i]/6
//   S1[i]    = P_T[i]
//   S2[i,j]  = sum_t G_t[i] v_t[j]
//   S3[i,j,k]= sum_t ( A2prev_t[i,j] + R_t[i] v_t[j] ) * v_t[k]
// where A2prev_t[i,j] = sum_{s<t} G_s[i] v_s[j] is the running S2 prefix
// (kept in a single register while looping t).

#define N_BATCH 32
#define LPATH   128
#define T_STEPS 127
#define C       48
#define C2      2304
#define C3      110592
#define OUT_PER_N (C + C2 + C3)      // 112944
#define PATH_PER_N (LPATH * C)       // 6144
#define TC (T_STEPS * C)             // 6096
#define WAVES_PER_BATCH (C2 / 64)    // 36

// ---------------- prep: v, G, R into ws; S1 into out ----------------
__global__ void sig_prep(const float* __restrict__ path,
                         float* __restrict__ ws,
                         float* __restrict__ out) {
    const int total = N_BATCH * TC;
    int e = blockIdx.x * blockDim.x + threadIdx.x;
    if (e < total) {
        int n = e / TC;
        int r = e - n * TC;
        int t = r / C;
        int i = r - t * C;
        const float* p = path + n * PATH_PER_N;
        float pt  = p[t * C + i];
        float pt1 = p[(t + 1) * C + i];
        float p0  = p[i];
        float v = pt1 - pt;
        float P = pt - p0;
        ws[e]             = v;                        // v
        ws[total + e]     = P + 0.5f * v;             // G
        ws[2 * total + e] = 0.5f * P + v * (1.0f / 6.0f); // R
    }
    if (e < N_BATCH * C) {
        int n = e / C;
        int i = e - n * C;
        const float* p = path + n * PATH_PER_N;
        out[n * OUT_PER_N + i] = p[(LPATH - 1) * C + i] - p[i];  // S1
    }
}

// ---------------- main: one thread per (i,j) row of S3 ----------------
__global__ __launch_bounds__(64) void sig_main(const float* __restrict__ ws,
                                               float* __restrict__ out) {
    const int total = N_BATCH * TC;
    int bid = blockIdx.x;                 // 0 .. 32*36-1
    int n = bid / WAVES_PER_BATCH;
    int w = bid - n * WAVES_PER_BATCH;
    int ij = w * 64 + threadIdx.x;        // 0..2303
    int i = ij / C;
    int j = ij - i * C;

    const float* __restrict__ v = ws + n * TC;
    const float* __restrict__ G = ws + total + n * TC;
    const float* __restrict__ R = ws + 2 * total + n * TC;

    float s3[C];
    #pragma unroll
    for (int k = 0; k < C; ++k) s3[k] = 0.0f;
    float a2 = 0.0f;

    #pragma unroll 1
    for (int t = 0; t < T_STEPS; ++t) {
        const float* vt = v + t * C;
        float4 v4[12];
        #pragma unroll
        for (int kk = 0; kk < 12; ++kk)
            v4[kk] = ((const float4*)vt)[kk];   // wave-uniform broadcast loads
        float vj = vt[j];
        float Gt = G[t * C + i];
        float Rt = R[t * C + i];
        float b = a2 + Rt * vj;   // B_t[i,j] uses A2prev (pre-update)
        a2 += Gt * vj;            // advance S2 prefix
        #pragma unroll
        for (int kk = 0; kk < 12; ++kk) {
            s3[4 * kk + 0] += b * v4[kk].x;
            s3[4 * kk + 1] += b * v4[kk].y;
            s3[4 * kk + 2] += b * v4[kk].z;
            s3[4 * kk + 3] += b * v4[kk].w;
        }
    }

    // S2: final prefix value
    out[n * OUT_PER_N + C + ij] = a2;

    // S3: 48 consecutive floats per row, 16B-aligned
    float4* dst = (float4*)(out + n * OUT_PER_N + C + C2 + (long)ij * C);
    #pragma unroll
    for (int kk = 0; kk < 12; ++kk)
        dst[kk] = make_float4(s3[4 * kk + 0], s3[4 * kk + 1],
                              s3[4 * kk + 2], s3[4 * kk + 3]);
}

extern "C" void kernel_launch(void* const* d_in, const int* in_sizes, int n_in,
                              void* d_out, int out_size, void* d_ws, size_t ws_size,
                              hipStream_t stream) {
    const float* path = (const float*)d_in[0];
    float* out = (float*)d_out;
    float* ws = (float*)d_ws;   // needs 3 * 32*127*48 * 4 B = 2.34 MB

    int prep_threads = N_BATCH * TC;                      // 195072
    int prep_blocks = (prep_threads + 255) / 256;         // 762
    sig_prep<<<prep_blocks, 256, 0, stream>>>(path, ws, out);

    sig_main<<<N_BATCH * WAVES_PER_BATCH, 64, 0, stream>>>(ws, out);
}